// Round 4
// baseline (4508.549 us; speedup 1.0000x reference)
//
#include <hip/hip_runtime.h>
#include <hip/hip_bf16.h>
#include <cstdint>
#include <cstddef>

// ---------------- model dims ----------------
#define B_SZ    2048
#define H_SZ    512
#define G4      2048      // 4*H
#define TSTEPS  21
#define MAXLEN  1000
#define KIN     1024      // input-K (L0 one-hot padded 1000->1024; L1 2H=1024)
#define NCLS    10

// ---------------- tiles ----------------
#define BM    128
#define BN    128
#define BKS   32          // K-tile for BOTH roles (step K=512 -> 16 it; gx K=1024 -> 32 it)
#define LDSKS 40          // LDS K-stride (80 B, 16B-aligned)
#define NITS  16
#define NITG  32
#define GP2   68          // gc f32 stride: all float4 16B-aligned, 2-way banks max
#define STEPBUF (3 * BM * LDSKS)   // shorts per step staging buffer (A,Bh,Bl) = 15360
#define GXBUF   (2 * BM * LDSKS)   // shorts per gx staging buffer (A,B) = 10240
// step dbuf 2*30720=61440 B; gx dbuf 2*20480=40960 B; gc 128*68*4=34816 B
#define SMEM_BYTES 61440  // 2 blocks/CU

typedef short bf16x8 __attribute__((ext_vector_type(8)));
typedef float f32x4  __attribute__((ext_vector_type(4)));
typedef unsigned short ushort8 __attribute__((ext_vector_type(8)));

__device__ __forceinline__ unsigned short f2bf(float f) {
  __hip_bfloat16 h = __float2bfloat16(f);
  unsigned short u; __builtin_memcpy(&u, &h, sizeof(u)); return u;
}
__device__ __forceinline__ float bf2f(unsigned short u) {
  __hip_bfloat16 h; __builtin_memcpy(&h, &u, sizeof(h)); return __bfloat162float(h);
}
__device__ __forceinline__ float sigmoidf_(float x) {
  x = fminf(fmaxf(x, -30.f), 30.f);
  return 1.f / (1.f + __expf(-x));
}
__device__ __forceinline__ float tanhf_(float x) {
  float xc = fminf(fmaxf(x, -15.f), 15.f);
  float e = __expf(2.f * xc);
  return (e - 1.f) / (e + 1.f);
}
// Raw barrier: LDS-visibility only (lgkmcnt), NO vmcnt drain -> global
// prefetch loads stay in flight across barriers (T4 counted-wait mechanism).
// sched_barrier(0) guards against hoisting past the asm (rule #18).
__device__ __forceinline__ void bar_lgkm() {
  asm volatile("s_waitcnt lgkmcnt(0)" ::: "memory");
  __builtin_amdgcn_s_barrier();
  __builtin_amdgcn_sched_barrier(0);
}
// gate permutation p = 4*j + type  <->  orig row type*512 + j (i,f,g,o)
__device__ __forceinline__ int rbase_of(int p) { return (p & 3) * H_SZ + (p >> 2); }

// ============================================================ prep kernels
__global__ void prep_rec_kernel(const float* __restrict__ w_hh,
                                unsigned short* __restrict__ Bhi,
                                unsigned short* __restrict__ Blo) {
  size_t idx = (size_t)blockIdx.x * blockDim.x + threadIdx.x;
  const size_t total = (size_t)2 * G4 * H_SZ;
  if (idx >= total) return;
  int k  = (int)(idx % H_SZ);
  size_t rowidx = idx / H_SZ;
  int p  = (int)(rowidx % G4);
  int dd = (int)(rowidx / G4);
  float w = w_hh[((size_t)dd * G4 + rbase_of(p)) * H_SZ + k];
  unsigned short h = f2bf(w);
  Bhi[idx] = h;
  Blo[idx] = f2bf(w - bf2f(h));
}

__global__ void prep_in0_kernel(const float* __restrict__ w_ih0,
                                unsigned short* __restrict__ Bin0) {  // [2,G4,KIN]
  size_t idx = (size_t)blockIdx.x * blockDim.x + threadIdx.x;
  const size_t total = (size_t)2 * G4 * KIN;
  if (idx >= total) return;
  int k  = (int)(idx % KIN);
  size_t rowidx = idx / KIN;
  int p  = (int)(rowidx % G4);
  int dd = (int)(rowidx / G4);
  float v = (k < MAXLEN) ? w_ih0[((size_t)dd * G4 + rbase_of(p)) * MAXLEN + k] : 0.f;
  Bin0[idx] = f2bf(v);
}

__global__ void prep_in1_kernel(const float* __restrict__ w_ih1,
                                unsigned short* __restrict__ Bin1) {  // [2,G4,KIN]
  size_t idx = (size_t)blockIdx.x * blockDim.x + threadIdx.x;
  const size_t total = (size_t)2 * G4 * KIN;
  if (idx >= total) return;
  int k  = (int)(idx % KIN);
  size_t rowidx = idx / KIN;
  int p  = (int)(rowidx % G4);
  int dd = (int)(rowidx / G4);
  Bin1[idx] = f2bf(w_ih1[((size_t)dd * G4 + rbase_of(p)) * KIN + k]);
}

__global__ void prep_b_kernel(const float* __restrict__ b_ih0,
                              const float* __restrict__ b_hh0,
                              const float* __restrict__ b_ih1,
                              const float* __restrict__ b_hh1,
                              float* __restrict__ bias0,
                              float* __restrict__ bias1) {
  int idx = blockIdx.x * blockDim.x + threadIdx.x;
  if (idx >= 2 * G4) return;
  int p  = idx % G4;
  int dd = idx / G4;
  int src = dd * G4 + rbase_of(p);
  bias0[idx] = b_ih0[src] + b_hh0[src];
  bias1[idx] = b_ih1[src] + b_hh1[src];
}

// one-hot bitmasks: bits[t][b][w] bit j set iff x[b, 32w+j]==t (pos<MAXLEN)
__global__ void prep_x_kernel(const int* __restrict__ x,
                              unsigned int* __restrict__ bits) {
  int idx = blockIdx.x * blockDim.x + threadIdx.x;
  if (idx >= B_SZ * 32) return;
  int b = idx >> 5;
  int w = idx & 31;
  const int* xr = x + (size_t)b * MAXLEN + w * 32;
  int xv[32];
#pragma unroll
  for (int j = 0; j < 32; ++j) {
    int k = w * 32 + j;
    xv[j] = (k < MAXLEN) ? xr[j] : -1;
  }
#pragma unroll
  for (int t = 0; t < TSTEPS; ++t) {
    unsigned int m = 0;
#pragma unroll
    for (int j = 0; j < 32; ++j)
      m |= (xv[j] == t) ? (1u << j) : 0u;
    bits[((size_t)t * B_SZ + b) * 32 + w] = m;
  }
}

// ============================================================
// STEP ROLE: 256 threads / 4 waves, 64x64 per-wave tiles (2x2 wave grid)
// -> A re-read x2, B re-read x2: 48 ds_read_b128/iter vs 80 with the old
// 2x4 wave grid (LDS pipe is the bottleneck). R3 pipeline kept: dbuf LDS,
// raw lgkm-only barriers, 2-deep named-register lookahead (rule #20).
// ============================================================
template <int LAYER>
__device__ void step_role(char* smraw, int sid, int step,
                          const unsigned short* __restrict__ Bhrec,   // [2,G4,512]
                          const unsigned short* __restrict__ Blrec,   // [2,G4,512]
                          const float* __restrict__ bias,             // [2,G4]
                          const unsigned short* __restrict__ h_in,    // [2,B,H]
                          unsigned short* __restrict__ h_out,
                          float* __restrict__ c_st,                   // [2,B,H]
                          unsigned short* __restrict__ seq_out,       // [T,B,2H] (L0)
                          float* __restrict__ zacc,                   // [B,2H]   (L1)
                          const float* __restrict__ emb_w,            // [21]     (L1)
                          const float* __restrict__ gxcur) {          // [2,B,G4]
  unsigned short* buf0 = (unsigned short*)smraw;
  unsigned short* buf1 = buf0 + STEPBUF;
  float*          gc   = (float*)smraw;            // epilogue reuse: [128][GP2] f32

  const int tid  = threadIdx.x;                    // 0..255
  const int lane = tid & 63;
  const int wave = tid >> 6;                       // 0..3
  const int wr   = wave >> 1;                      // 0..1
  const int wc   = wave & 1;                       // 0..1
  const int q    = lane >> 4;
  const int r16  = lane & 15;

  const int xcd  = sid & 7;
  const int slot = sid >> 3;
  const int nb   = xcd * 2 + (slot & 1);
  const int mb   = (slot >> 1) & 15;
  const int d    = slot >> 5;
  const int tcur = d ? (TSTEPS - 1 - step) : step;
  const int n0   = nb * BN;
  const int m0   = mb * BM;

  const unsigned short* Bh_mat = Bhrec + (size_t)d * G4 * H_SZ;
  const unsigned short* Bl_mat = Blrec + (size_t)d * G4 * H_SZ;
  const unsigned short* Ah     = h_in + (size_t)d * B_SZ * H_SZ;

  float bval[4];
#pragma unroll
  for (int nt = 0; nt < 4; ++nt)
    bval[nt] = bias[d * G4 + n0 + wc * 64 + nt * 16 + r16];

  f32x4 acc[4][4];
#pragma unroll
  for (int mt = 0; mt < 4; ++mt)
#pragma unroll
    for (int nt = 0; nt < 4; ++nt) {
      f32x4 z = {0.f, 0.f, 0.f, 0.f};
      acc[mt][nt] = z;
    }

  // staging: each of 3 tiles is 128x32 shorts = 512 ushort8-chunks; 256
  // threads -> 2 chunks/thread/tile at rows ro and ro+64.
  const int ro = tid >> 2;           // 0..63
  const int oo = (tid & 3) * 8;

  // two NAMED in-flight register sets (static indexing only, rule #20)
  ushort8 pbhA0, pbhA1, pblA0, pblA1, pvaA0, pvaA1;
  ushort8 pbhB0, pbhB1, pblB0, pblB1, pvaB0, pvaB1;
  auto loadA = [&](int kt) {
    const int k0 = kt * BKS;
    pbhA0 = *(const ushort8*)(Bh_mat + (size_t)(n0 + ro) * H_SZ + k0 + oo);
    pbhA1 = *(const ushort8*)(Bh_mat + (size_t)(n0 + ro + 64) * H_SZ + k0 + oo);
    pblA0 = *(const ushort8*)(Bl_mat + (size_t)(n0 + ro) * H_SZ + k0 + oo);
    pblA1 = *(const ushort8*)(Bl_mat + (size_t)(n0 + ro + 64) * H_SZ + k0 + oo);
    pvaA0 = *(const ushort8*)(Ah + (size_t)(m0 + ro) * H_SZ + k0 + oo);
    pvaA1 = *(const ushort8*)(Ah + (size_t)(m0 + ro + 64) * H_SZ + k0 + oo);
  };
  auto loadB = [&](int kt) {
    const int k0 = kt * BKS;
    pbhB0 = *(const ushort8*)(Bh_mat + (size_t)(n0 + ro) * H_SZ + k0 + oo);
    pbhB1 = *(const ushort8*)(Bh_mat + (size_t)(n0 + ro + 64) * H_SZ + k0 + oo);
    pblB0 = *(const ushort8*)(Bl_mat + (size_t)(n0 + ro) * H_SZ + k0 + oo);
    pblB1 = *(const ushort8*)(Bl_mat + (size_t)(n0 + ro + 64) * H_SZ + k0 + oo);
    pvaB0 = *(const ushort8*)(Ah + (size_t)(m0 + ro) * H_SZ + k0 + oo);
    pvaB1 = *(const ushort8*)(Ah + (size_t)(m0 + ro + 64) * H_SZ + k0 + oo);
  };
  auto storeA = [&](unsigned short* sA) {
    unsigned short* sBh = sA + BM * LDSKS;
    unsigned short* sBl = sBh + BM * LDSKS;
    *(ushort8*)(sA + ro * LDSKS + oo)         = pvaA0;
    *(ushort8*)(sA + (ro + 64) * LDSKS + oo)  = pvaA1;
    *(ushort8*)(sBh + ro * LDSKS + oo)        = pbhA0;
    *(ushort8*)(sBh + (ro + 64) * LDSKS + oo) = pbhA1;
    *(ushort8*)(sBl + ro * LDSKS + oo)        = pblA0;
    *(ushort8*)(sBl + (ro + 64) * LDSKS + oo) = pblA1;
  };
  auto storeB = [&](unsigned short* sA) {
    unsigned short* sBh = sA + BM * LDSKS;
    unsigned short* sBl = sBh + BM * LDSKS;
    *(ushort8*)(sA + ro * LDSKS + oo)         = pvaB0;
    *(ushort8*)(sA + (ro + 64) * LDSKS + oo)  = pvaB1;
    *(ushort8*)(sBh + ro * LDSKS + oo)        = pbhB0;
    *(ushort8*)(sBh + (ro + 64) * LDSKS + oo) = pbhB1;
    *(ushort8*)(sBl + ro * LDSKS + oo)        = pblB0;
    *(ushort8*)(sBl + (ro + 64) * LDSKS + oo) = pblB1;
  };
  auto compute = [&](const unsigned short* sA) {
    const unsigned short* sBh = sA + BM * LDSKS;
    const unsigned short* sBl = sBh + BM * LDSKS;
    bf16x8 af[4], bh[4];
#pragma unroll
    for (int mt = 0; mt < 4; ++mt)
      af[mt] = *(const bf16x8*)(sA + (wr * 64 + mt * 16 + r16) * LDSKS + q * 8);
#pragma unroll
    for (int nt = 0; nt < 4; ++nt)
      bh[nt] = *(const bf16x8*)(sBh + (wc * 64 + nt * 16 + r16) * LDSKS + q * 8);
#pragma unroll
    for (int mt = 0; mt < 4; ++mt)
#pragma unroll
      for (int nt = 0; nt < 4; ++nt)
        acc[mt][nt] = __builtin_amdgcn_mfma_f32_16x16x32_bf16(af[mt], bh[nt], acc[mt][nt], 0, 0, 0);
    bf16x8 bl[4];
#pragma unroll
    for (int nt = 0; nt < 4; ++nt)
      bl[nt] = *(const bf16x8*)(sBl + (wc * 64 + nt * 16 + r16) * LDSKS + q * 8);
#pragma unroll
    for (int mt = 0; mt < 4; ++mt)
#pragma unroll
      for (int nt = 0; nt < 4; ++nt)
        acc[mt][nt] = __builtin_amdgcn_mfma_f32_16x16x32_bf16(af[mt], bl[nt], acc[mt][nt], 0, 0, 0);
  };

  // epilogue-operand prefetch registers (cell layout; static indices only)
  float4 gpre[2][8];
  float  cpre[2][8];
  float  zpre[2][8];

  loadA(0);
  loadB(1);

  for (int kt2 = 0; kt2 < NITS; kt2 += 2) {
    // ---- even phase (data set A -> buf0) ----
    storeA(buf0);                 // counted vmcnt: loaded 2 iters ago
    bar_lgkm();                   // LDS visible; global loads stay in flight
    if (kt2 + 2 < NITS) loadA(kt2 + 2);
    compute(buf0);

    // ---- odd phase (data set B -> buf1) ----
    storeB(buf1);
    bar_lgkm();
    if (kt2 + 3 < NITS) loadB(kt2 + 3);
    if (kt2 == NITS - 2) {
      // Both staging sets are dead here -> register headroom for the
      // coalesced epilogue prefetch; drains at the post-loop __syncthreads
      // with ~1 full iter + gc-write phase of cover.
      const int jb = nb * 32;
#pragma unroll
      for (int cc = 0; cc < 2; ++cc)
#pragma unroll
        for (int it = 0; it < 8; ++it) {
          int cell = it * 256 + tid;
          int rl = cell >> 4, jq = cell & 15;
          int b = m0 + rl;
          int j = jb + cc * 16 + jq;
          gpre[cc][it] = *(const float4*)(gxcur + ((size_t)d * B_SZ + b) * G4 + (size_t)j * 4);
          cpre[cc][it] = c_st[((size_t)d * B_SZ + b) * H_SZ + j];
          if (LAYER == 1)
            zpre[cc][it] = zacc[(size_t)b * (2 * H_SZ) + d * H_SZ + j];
        }
    }
    compute(buf1);
  }
  __syncthreads();   // full drain (incl. epilogue prefetch) before gc reuse

  // ---- epilogue: 2 chunks of 64 gate-cols through gc[128][GP2] ----
  // C/D layout: col=lane&15, row=(lane>>4)*4+reg  [m89/m91 verified]
  const int jbase = nb * 32;
  const float ew = (LAYER == 1) ? emb_w[tcur] : 0.f;

#pragma unroll
  for (int cc = 0; cc < 2; ++cc) {
    if (wc == cc) {
#pragma unroll
      for (int mt = 0; mt < 4; ++mt)
#pragma unroll
        for (int nt = 0; nt < 4; ++nt)
#pragma unroll
          for (int r = 0; r < 4; ++r) {
            int ml = wr * 64 + mt * 16 + q * 4 + r;
            gc[ml * GP2 + nt * 16 + r16] = acc[mt][nt][r] + bval[nt];
          }
    }
    __syncthreads();

#pragma unroll
    for (int it = 0; it < 8; ++it) {
      int cell = it * 256 + tid;
      int rl = cell >> 4, jq = cell & 15;
      int b = m0 + rl;
      int j = jbase + cc * 16 + jq;
      float4 g = *(const float4*)(&gc[rl * GP2 + jq * 4]);
      const float4 gx = gpre[cc][it];
      g.x += gx.x; g.y += gx.y; g.z += gx.z; g.w += gx.w;
      float si = sigmoidf_(g.x);
      float sf = sigmoidf_(g.y);
      float tg = tanhf_(g.z);
      float so = sigmoidf_(g.w);
      size_t cidx = ((size_t)d * B_SZ + b) * H_SZ + j;
      float cn = sf * cpre[cc][it] + si * tg;
      float hv = so * tanhf_(cn);
      c_st[cidx] = cn;
      h_out[cidx] = f2bf(hv);
      if (LAYER == 0) {
        seq_out[((size_t)tcur * B_SZ + b) * (2 * H_SZ) + d * H_SZ + j] = f2bf(hv);
      } else {
        zacc[(size_t)b * (2 * H_SZ) + d * H_SZ + j] = zpre[cc][it] + ew * hv;
      }
    }
    if (cc == 0) __syncthreads();
  }
}

// ============================================================
// GX ROLE: dense input-projection GEMM for step gx_step. 256 threads /
// 4 waves, 64x64 wave tiles (32 reads/iter vs 48). BK=32, dbuf LDS, raw
// lgkm-only barriers, 2-deep named-register lookahead.
// L0: A = one-hot from xbits; L1: A = seq0[t].
// ============================================================
template <int LAYER>
__device__ void gx_role(char* smraw, int gid, int gx_step,
                        const unsigned int* __restrict__ xbits,     // [21,B,32]
                        const unsigned short* __restrict__ seq0,    // [T,B,2H]
                        const unsigned short* __restrict__ Bin,     // [2,G4,KIN]
                        float* __restrict__ gxnext) {               // [2,B,G4]
  if (gx_step >= TSTEPS) return;

  unsigned short* buf0 = (unsigned short*)smraw;
  unsigned short* buf1 = buf0 + GXBUF;

  const int tid  = threadIdx.x;                    // 0..255
  const int lane = tid & 63;
  const int wave = tid >> 6;                       // 0..3
  const int wr   = wave >> 1;                      // 0..1
  const int wc   = wave & 1;                       // 0..1
  const int q    = lane >> 4;
  const int r16  = lane & 15;

  const int xcd  = gid & 7;
  const int slot = gid >> 3;
  const int nb   = xcd * 2 + (slot & 1);
  const int mb   = (slot >> 1) & 15;
  const int d    = slot >> 5;
  const int tg   = d ? (TSTEPS - 1 - gx_step) : gx_step;
  const int n0   = nb * BN;
  const int m0   = mb * BM;

  const unsigned short* Bmat = Bin + (size_t)d * G4 * KIN;
  const unsigned char*  xrow = (const unsigned char*)xbits + ((size_t)tg * B_SZ) * (KIN / 8);
  const unsigned short* Asrc = seq0 + (size_t)tg * B_SZ * (2 * H_SZ);

  f32x4 acc[4][4];
#pragma unroll
  for (int mt = 0; mt < 4; ++mt)
#pragma unroll
    for (int nt = 0; nt < 4; ++nt) {
      f32x4 z = {0.f, 0.f, 0.f, 0.f};
      acc[mt][nt] = z;
    }

  const int ro = tid >> 2;           // 0..63
  const int oo = (tid & 3) * 8;

  ushort8 pbA0, pbA1, paA0, paA1, pbB0, pbB1, paB0, paB1;
  unsigned int bvA0, bvA1, bvB0, bvB1;
  auto loadA = [&](int kt) {
    const int k0 = kt * BKS;
    pbA0 = *(const ushort8*)(Bmat + (size_t)(n0 + ro) * KIN + k0 + oo);
    pbA1 = *(const ushort8*)(Bmat + (size_t)(n0 + ro + 64) * KIN + k0 + oo);
    if (LAYER == 0) {
      bvA0 = xrow[(size_t)(m0 + ro) * (KIN / 8) + (k0 + oo) / 8];
      bvA1 = xrow[(size_t)(m0 + ro + 64) * (KIN / 8) + (k0 + oo) / 8];
    } else {
      paA0 = *(const ushort8*)(Asrc + (size_t)(m0 + ro) * (2 * H_SZ) + k0 + oo);
      paA1 = *(const ushort8*)(Asrc + (size_t)(m0 + ro + 64) * (2 * H_SZ) + k0 + oo);
    }
  };
  auto loadB = [&](int kt) {
    const int k0 = kt * BKS;
    pbB0 = *(const ushort8*)(Bmat + (size_t)(n0 + ro) * KIN + k0 + oo);
    pbB1 = *(const ushort8*)(Bmat + (size_t)(n0 + ro + 64) * KIN + k0 + oo);
    if (LAYER == 0) {
      bvB0 = xrow[(size_t)(m0 + ro) * (KIN / 8) + (k0 + oo) / 8];
      bvB1 = xrow[(size_t)(m0 + ro + 64) * (KIN / 8) + (k0 + oo) / 8];
    } else {
      paB0 = *(const ushort8*)(Asrc + (size_t)(m0 + ro) * (2 * H_SZ) + k0 + oo);
      paB1 = *(const ushort8*)(Asrc + (size_t)(m0 + ro + 64) * (2 * H_SZ) + k0 + oo);
    }
  };
  auto expand = [&](unsigned int bv, unsigned short* dst) {
    unsigned int pk[4];
#pragma unroll
    for (int e = 0; e < 4; ++e) {
      pk[e] = (((bv >> (2 * e)) & 1u) ? 0x3F80u : 0u)
            | (((bv >> (2 * e + 1)) & 1u) ? 0x3F800000u : 0u);
    }
    *(uint4*)dst = make_uint4(pk[0], pk[1], pk[2], pk[3]);
  };
  auto storeA = [&](unsigned short* sA) {
    unsigned short* sB = sA + BM * LDSKS;
    if (LAYER == 0) {
      expand(bvA0, sA + ro * LDSKS + oo);
      expand(bvA1, sA + (ro + 64) * LDSKS + oo);
    } else {
      *(ushort8*)(sA + ro * LDSKS + oo)        = paA0;
      *(ushort8*)(sA + (ro + 64) * LDSKS + oo) = paA1;
    }
    *(ushort8*)(sB + ro * LDSKS + oo)        = pbA0;
    *(ushort8*)(sB + (ro + 64) * LDSKS + oo) = pbA1;
  };
  auto storeB = [&](unsigned short* sA) {
    unsigned short* sB = sA + BM * LDSKS;
    if (LAYER == 0) {
      expand(bvB0, sA + ro * LDSKS + oo);
      expand(bvB1, sA + (ro + 64) * LDSKS + oo);
    } else {
      *(ushort8*)(sA + ro * LDSKS + oo)        = paB0;
      *(ushort8*)(sA + (ro + 64) * LDSKS + oo) = paB1;
    }
    *(ushort8*)(sB + ro * LDSKS + oo)        = pbB0;
    *(ushort8*)(sB + (ro + 64) * LDSKS + oo) = pbB1;
  };
  auto compute = [&](const unsigned short* sA) {
    const unsigned short* sB = sA + BM * LDSKS;
    bf16x8 af[4], bh[4];
#pragma unroll
    for (int mt = 0; mt < 4; ++mt)
      af[mt] = *(const bf16x8*)(sA + (wr * 64 + mt * 16 + r16) * LDSKS + q * 8);
#pragma unroll
    for (int nt = 0; nt < 4; ++nt)
      bh[nt] = *(const bf16x8*)(sB + (wc * 64 + nt * 16 + r16) * LDSKS + q * 8);
#pragma unroll
    for (int mt = 0; mt < 4; ++mt)
#pragma unroll
      for (int nt = 0; nt < 4; ++nt)
        acc[mt][nt] = __builtin_amdgcn_mfma_f32_16x16x32_bf16(af[mt], bh[nt], acc[mt][nt], 0, 0, 0);
  };

  loadA(0);
  loadB(1);

  for (int kt2 = 0; kt2 < NITG; kt2 += 2) {
    storeA(buf0);
    bar_lgkm();
    if (kt2 + 2 < NITG) loadA(kt2 + 2);
    compute(buf0);

    storeB(buf1);
    bar_lgkm();
    if (kt2 + 3 < NITG) loadB(kt2 + 3);
    compute(buf1);
  }

  // write gx (C/D layout: col=lane&15, row=quad*4+reg)
#pragma unroll
  for (int mt = 0; mt < 4; ++mt)
#pragma unroll
    for (int nt = 0; nt < 4; ++nt)
#pragma unroll
      for (int r = 0; r < 4; ++r) {
        int row = m0 + wr * 64 + mt * 16 + q * 4 + r;
        int col = n0 + wc * 64 + nt * 16 + r16;
        gxnext[((size_t)d * B_SZ + row) * G4 + col] = acc[mt][nt][r];
      }
}

// ============================================================ fused launcher
// (256,2): 4 waves/block, 2 blocks/CU (LDS-bound) = 2 waves/SIMD,
// VGPR budget 256 for the 4x4 acc + epilogue prefetch state.
template <int LAYER>
__global__ __launch_bounds__(256, 2)
void fused_kernel(const unsigned int* __restrict__ xbits,
                  const unsigned short* __restrict__ seq0,
                  const unsigned short* __restrict__ Bin,
                  const unsigned short* __restrict__ Bhrec,
                  const unsigned short* __restrict__ Blrec,
                  const float* __restrict__ bias,
                  const unsigned short* __restrict__ h_in,
                  unsigned short* __restrict__ h_out,
                  float* __restrict__ c_st,
                  unsigned short* __restrict__ seq_out,
                  float* __restrict__ zacc,
                  const float* __restrict__ emb_w,
                  const float* __restrict__ gxcur,
                  float* __restrict__ gxnext,
                  int step, int gx_step) {
  extern __shared__ char smraw[];
  const int bid = blockIdx.x;
  if ((bid & 1) == 0) {
    step_role<LAYER>(smraw, bid >> 1, step, Bhrec, Blrec, bias, h_in, h_out,
                     c_st, seq_out, zacc, emb_w, gxcur);
  } else {
    gx_role<LAYER>(smraw, bid >> 1, gx_step, xbits, seq0, Bin, gxnext);
  }
}

template <int LAYER>
__global__ __launch_bounds__(256, 2)
void gx_only_kernel(const unsigned int* __restrict__ xbits,
                    const unsigned short* __restrict__ seq0,
                    const unsigned short* __restrict__ Bin,
                    float* __restrict__ gxnext, int gx_step) {
  extern __shared__ char smraw[];
  gx_role<LAYER>(smraw, blockIdx.x, gx_step, xbits, seq0, Bin, gxnext);
}

// ============================================================ final
__global__ __launch_bounds__(256)
void final_kernel(const float* __restrict__ zacc,
                  const float* __restrict__ emb_b,
                  const float* __restrict__ fc_w,
                  const float* __restrict__ fc_b,
                  float* __restrict__ out) {
  const int b = blockIdx.x;
  const int tid = threadIdx.x;
  const int c0 = tid * 4;

  const float zb = emb_b[0];
  const float4 z4 = *(const float4*)(zacc + (size_t)b * (2 * H_SZ) + c0);
  float z0 = z4.x + zb, z1 = z4.y + zb, z2 = z4.z + zb, z3 = z4.w + zb;

  float part[NCLS];
#pragma unroll
  for (int nc = 0; nc < NCLS; ++nc) {
    const float4 f = *(const float4*)(fc_w + (size_t)nc * (2 * H_SZ) + c0);
    part[nc] = z0 * f.x + z1 * f.y + z2 * f.z + z3 * f.w;
  }
#pragma unroll
  for (int nc = 0; nc < NCLS; ++nc)
#pragma unroll
    for (int off2 = 32; off2 > 0; off2 >>= 1)
      part[nc] += __shfl_down(part[nc], off2);

  __shared__ float red[4][NCLS];
  if ((tid & 63) == 0) {
#pragma unroll
    for (int nc = 0; nc < NCLS; ++nc) red[tid >> 6][nc] = part[nc];
  }
  __syncthreads();
  if (tid < NCLS) {
    float s = red[0][tid] + red[1][tid] + red[2][tid] + red[3][tid] + fc_b[tid];
    out[b * NCLS + tid] = s;
  }
}

// ============================================================
extern "C" void kernel_launch(void* const* d_in, const int* in_sizes, int n_in,
                              void* d_out, int out_size, void* d_ws, size_t ws_size,
                              hipStream_t stream) {
  (void)in_sizes; (void)n_in; (void)out_size; (void)ws_size;

  const int*   x     = (const int*)d_in[0];
  const float* w_ih0 = (const float*)d_in[1];
  const float* w_hh0 = (const float*)d_in[2];
  const float* b_ih0 = (const float*)d_in[3];
  const float* b_hh0 = (const float*)d_in[4];
  const float* w_ih1 = (const float*)d_in[5];
  const float* w_hh1 = (const float*)d_in[6];
  const float* b_ih1 = (const float*)d_in[7];
  const float* b_hh1 = (const float*)d_in[8];
  const float* emb_w = (const float*)d_in[9];
  const float* emb_b = (const float*)d_in[10];
  const float* fc_w  = (const float*)d_in[11];
  const float* fc_b  = (const float*)d_in[12];

  // -------- workspace (~211 MB) --------
  char* ws = (char*)d_ws;
  size_t off = 0;
  auto alloc = [&](size_t bytes) -> void* {
    void* p = ws + off;
    off += (bytes + 255) & ~(size_t)255;
    return p;
  };
  const size_t bin_b  = (size_t)2 * G4 * KIN * 2;               // 8.39 MB
  const size_t brec_b = (size_t)2 * G4 * H_SZ * 2;              // 4.19 MB
  const size_t xb_b   = (size_t)TSTEPS * B_SZ * 32 * 4;         // 5.50 MB
  const size_t h_b    = (size_t)2 * B_SZ * H_SZ * 2;            // 4.19 MB
  const size_t c_b    = (size_t)2 * B_SZ * H_SZ * 4;            // 8.39 MB
  const size_t gx_b   = (size_t)2 * B_SZ * G4 * 4;              // 33.55 MB
  const size_t seq_b  = (size_t)TSTEPS * B_SZ * (2 * H_SZ) * 2; // 88.08 MB
  const size_t z_b    = (size_t)B_SZ * (2 * H_SZ) * 4;          // 8.39 MB

  unsigned short* Bin0  = (unsigned short*)alloc(bin_b);   // L0-only; zacc aliases
  unsigned short* Bin1  = (unsigned short*)alloc(bin_b);
  unsigned short* Bh0   = (unsigned short*)alloc(brec_b);
  unsigned short* Bl0   = (unsigned short*)alloc(brec_b);
  unsigned short* Bh1   = (unsigned short*)alloc(brec_b);
  unsigned short* Bl1   = (unsigned short*)alloc(brec_b);
  float*          bias0 = (float*)alloc((size_t)2 * G4 * 4);
  float*          bias1 = (float*)alloc((size_t)2 * G4 * 4);
  unsigned int*   xbits = (unsigned int*)alloc(xb_b);
  unsigned short* hA    = (unsigned short*)alloc(h_b);
  unsigned short* hB    = (unsigned short*)alloc(h_b);
  float*          cst   = (float*)alloc(c_b);
  float*          gxA   = (float*)alloc(gx_b);
  float*          gxB   = (float*)alloc(gx_b);
  unsigned short* seq0  = (unsigned short*)alloc(seq_b);
  float*          zacc  = (float*)Bin0;   // Bin0 (8.39 MB) dead after layer 0; z_b == bin_b

  // -------- prep --------
  {
    size_t ti = (size_t)2 * G4 * KIN;
    prep_in0_kernel<<<(int)((ti + 255) / 256), 256, 0, stream>>>(w_ih0, Bin0);
    prep_in1_kernel<<<(int)((ti + 255) / 256), 256, 0, stream>>>(w_ih1, Bin1);
    size_t tr = (size_t)2 * G4 * H_SZ;
    prep_rec_kernel<<<(int)((tr + 255) / 256), 256, 0, stream>>>(w_hh0, Bh0, Bl0);
    prep_rec_kernel<<<(int)((tr + 255) / 256), 256, 0, stream>>>(w_hh1, Bh1, Bl1);
    prep_b_kernel<<<16, 256, 0, stream>>>(b_ih0, b_hh0, b_ih1, b_hh1, bias0, bias1);
    prep_x_kernel<<<(B_SZ * 32 + 255) / 256, 256, 0, stream>>>(x, xbits);
  }

  // -------- layer 0 --------
  hipMemsetAsync(hA, 0, h_b, stream);
  hipMemsetAsync(cst, 0, c_b, stream);
  gx_only_kernel<0><<<512, 256, SMEM_BYTES, stream>>>(xbits, nullptr, Bin0, gxA, 0);
  for (int s = 0; s < TSTEPS; ++s) {
    const unsigned short* hin  = (s & 1) ? hB : hA;
    unsigned short*       hout = (s & 1) ? hA : hB;
    float* cur = (s & 1) ? gxB : gxA;
    float* nxt = (s & 1) ? gxA : gxB;
    fused_kernel<0><<<1024, 256, SMEM_BYTES, stream>>>(
        xbits, nullptr, Bin0, Bh0, Bl0, bias0, hin, hout, cst,
        seq0, nullptr, nullptr, cur, nxt, s, s + 1);
  }

  // -------- layer 1 --------
  hipMemsetAsync(hA, 0, h_b, stream);
  hipMemsetAsync(cst, 0, c_b, stream);
  hipMemsetAsync(zacc, 0, z_b, stream);
  gx_only_kernel<1><<<512, 256, SMEM_BYTES, stream>>>(nullptr, seq0, Bin1, gxA, 0);
  for (int s = 0; s < TSTEPS; ++s) {
    const unsigned short* hin  = (s & 1) ? hB : hA;
    unsigned short*       hout = (s & 1) ? hA : hB;
    float* cur = (s & 1) ? gxB : gxA;
    float* nxt = (s & 1) ? gxA : gxB;
    fused_kernel<1><<<1024, 256, SMEM_BYTES, stream>>>(
        nullptr, seq0, Bin1, Bh1, Bl1, bias1, hin, hout, cst,
        nullptr, zacc, emb_w, cur, nxt, s, s + 1);
  }

  // -------- fc --------
  final_kernel<<<B_SZ, 256, 0, stream>>>(zacc, emb_b, fc_w, fc_b, (float*)d_out);
}

// Round 5
// 2747.456 us; speedup vs baseline: 1.6410x; 1.6410x over previous
//
#include <hip/hip_runtime.h>
#include <hip/hip_bf16.h>
#include <cstdint>
#include <cstddef>

// ---------------- model dims ----------------
#define B_SZ    2048
#define H_SZ    512
#define G4      2048      // 4*H
#define TSTEPS  21
#define MAXLEN  1000
#define KIN     1024      // input-K (L0 one-hot padded 1000->1024; L1 2H=1024)
#define NCLS    10

// ---------------- tiles ----------------
#define BM    128
#define BN    128
#define BKS   32          // K-tile for BOTH roles (step K=512 -> 16 it; gx K=1024 -> 32 it)
#define LDSKS 40          // LDS K-stride (80 B, 16B-aligned)
#define NITS  16
#define NITG  32
#define GP2   68          // gc f32 stride: all float4 16B-aligned, 2-way banks max
#define STEPBUF (3 * BM * LDSKS)   // shorts per step staging buffer (A,Bh,Bl) = 15360
#define GXBUF   (2 * BM * LDSKS)   // shorts per gx staging buffer (A,B) = 10240
// step dbuf 2*30720=61440 B; gx dbuf 2*20480=40960 B; gc 128*68*4=34816 B
#define SMEM_BYTES 61440  // 2 blocks/CU

typedef short bf16x8 __attribute__((ext_vector_type(8)));
typedef float f32x4  __attribute__((ext_vector_type(4)));
typedef unsigned short ushort8 __attribute__((ext_vector_type(8)));

__device__ __forceinline__ unsigned short f2bf(float f) {
  __hip_bfloat16 h = __float2bfloat16(f);
  unsigned short u; __builtin_memcpy(&u, &h, sizeof(u)); return u;
}
__device__ __forceinline__ float bf2f(unsigned short u) {
  __hip_bfloat16 h; __builtin_memcpy(&h, &u, sizeof(h)); return __bfloat162float(h);
}
__device__ __forceinline__ float sigmoidf_(float x) {
  x = fminf(fmaxf(x, -30.f), 30.f);
  return 1.f / (1.f + __expf(-x));
}
__device__ __forceinline__ float tanhf_(float x) {
  float xc = fminf(fmaxf(x, -15.f), 15.f);
  float e = __expf(2.f * xc);
  return (e - 1.f) / (e + 1.f);
}
// Raw barrier: LDS-visibility only (lgkmcnt), NO vmcnt drain -> global
// prefetch loads stay in flight across barriers (T4 counted-wait mechanism).
// sched_barrier(0) guards against hoisting past the asm (rule #18).
__device__ __forceinline__ void bar_lgkm() {
  asm volatile("s_waitcnt lgkmcnt(0)" ::: "memory");
  __builtin_amdgcn_s_barrier();
  __builtin_amdgcn_sched_barrier(0);
}
// gate permutation p = 4*j + type  <->  orig row type*512 + j (i,f,g,o)
__device__ __forceinline__ int rbase_of(int p) { return (p & 3) * H_SZ + (p >> 2); }

// ============================================================ prep kernels
__global__ void prep_rec_kernel(const float* __restrict__ w_hh,
                                unsigned short* __restrict__ Bhi,
                                unsigned short* __restrict__ Blo) {
  size_t idx = (size_t)blockIdx.x * blockDim.x + threadIdx.x;
  const size_t total = (size_t)2 * G4 * H_SZ;
  if (idx >= total) return;
  int k  = (int)(idx % H_SZ);
  size_t rowidx = idx / H_SZ;
  int p  = (int)(rowidx % G4);
  int dd = (int)(rowidx / G4);
  float w = w_hh[((size_t)dd * G4 + rbase_of(p)) * H_SZ + k];
  unsigned short h = f2bf(w);
  Bhi[idx] = h;
  Blo[idx] = f2bf(w - bf2f(h));
}

__global__ void prep_in0_kernel(const float* __restrict__ w_ih0,
                                unsigned short* __restrict__ Bin0) {  // [2,G4,KIN]
  size_t idx = (size_t)blockIdx.x * blockDim.x + threadIdx.x;
  const size_t total = (size_t)2 * G4 * KIN;
  if (idx >= total) return;
  int k  = (int)(idx % KIN);
  size_t rowidx = idx / KIN;
  int p  = (int)(rowidx % G4);
  int dd = (int)(rowidx / G4);
  float v = (k < MAXLEN) ? w_ih0[((size_t)dd * G4 + rbase_of(p)) * MAXLEN + k] : 0.f;
  Bin0[idx] = f2bf(v);
}

__global__ void prep_in1_kernel(const float* __restrict__ w_ih1,
                                unsigned short* __restrict__ Bin1) {  // [2,G4,KIN]
  size_t idx = (size_t)blockIdx.x * blockDim.x + threadIdx.x;
  const size_t total = (size_t)2 * G4 * KIN;
  if (idx >= total) return;
  int k  = (int)(idx % KIN);
  size_t rowidx = idx / KIN;
  int p  = (int)(rowidx % G4);
  int dd = (int)(rowidx / G4);
  Bin1[idx] = f2bf(w_ih1[((size_t)dd * G4 + rbase_of(p)) * KIN + k]);
}

__global__ void prep_b_kernel(const float* __restrict__ b_ih0,
                              const float* __restrict__ b_hh0,
                              const float* __restrict__ b_ih1,
                              const float* __restrict__ b_hh1,
                              float* __restrict__ bias0,
                              float* __restrict__ bias1) {
  int idx = blockIdx.x * blockDim.x + threadIdx.x;
  if (idx >= 2 * G4) return;
  int p  = idx % G4;
  int dd = idx / G4;
  int src = dd * G4 + rbase_of(p);
  bias0[idx] = b_ih0[src] + b_hh0[src];
  bias1[idx] = b_ih1[src] + b_hh1[src];
}

// one-hot bitmasks: bits[t][b][w] bit j set iff x[b, 32w+j]==t (pos<MAXLEN)
__global__ void prep_x_kernel(const int* __restrict__ x,
                              unsigned int* __restrict__ bits) {
  int idx = blockIdx.x * blockDim.x + threadIdx.x;
  if (idx >= B_SZ * 32) return;
  int b = idx >> 5;
  int w = idx & 31;
  const int* xr = x + (size_t)b * MAXLEN + w * 32;
  int xv[32];
#pragma unroll
  for (int j = 0; j < 32; ++j) {
    int k = w * 32 + j;
    xv[j] = (k < MAXLEN) ? xr[j] : -1;
  }
#pragma unroll
  for (int t = 0; t < TSTEPS; ++t) {
    unsigned int m = 0;
#pragma unroll
    for (int j = 0; j < 32; ++j)
      m |= (xv[j] == t) ? (1u << j) : 0u;
    bits[((size_t)t * B_SZ + b) * 32 + w] = m;
  }
}

// ============================================================
// STEP ROLE: 16 recurrent K-iters (hi+lo), double-buffered LDS, raw
// lgkm-only barriers (1/iter), 2-deep named-register lookahead (rule #20).
// R5: wave grid 2(M)x4(N) (wave tile 64x32) -> 64 ds_read_b128/iter vs 80
// with 4x2. Same MFMA count, same acc size, same occupancy as R3.
// ============================================================
template <int LAYER>
__device__ void step_role(char* smraw, int sid, int step,
                          const unsigned short* __restrict__ Bhrec,   // [2,G4,512]
                          const unsigned short* __restrict__ Blrec,   // [2,G4,512]
                          const float* __restrict__ bias,             // [2,G4]
                          const unsigned short* __restrict__ h_in,    // [2,B,H]
                          unsigned short* __restrict__ h_out,
                          float* __restrict__ c_st,                   // [2,B,H]
                          unsigned short* __restrict__ seq_out,       // [T,B,2H] (L0)
                          float* __restrict__ zacc,                   // [B,2H]   (L1)
                          const float* __restrict__ emb_w,            // [21]     (L1)
                          const float* __restrict__ gxcur) {          // [2,B,G4]
  unsigned short* buf0 = (unsigned short*)smraw;
  unsigned short* buf1 = buf0 + STEPBUF;
  float*          gc   = (float*)smraw;            // epilogue reuse: [128][GP2] f32

  const int tid  = threadIdx.x;
  const int lane = tid & 63;
  const int wave = tid >> 6;                       // 0..7
  const int wr   = wave >> 2;                      // 0..1  (M)
  const int wc   = wave & 3;                       // 0..3  (N)
  const int q    = lane >> 4;
  const int r16  = lane & 15;

  const int xcd  = sid & 7;
  const int slot = sid >> 3;
  const int nb   = xcd * 2 + (slot & 1);
  const int mb   = (slot >> 1) & 15;
  const int d    = slot >> 5;
  const int tcur = d ? (TSTEPS - 1 - step) : step;
  const int n0   = nb * BN;
  const int m0   = mb * BM;

  const unsigned short* Bh_mat = Bhrec + (size_t)d * G4 * H_SZ;
  const unsigned short* Bl_mat = Blrec + (size_t)d * G4 * H_SZ;
  const unsigned short* Ah     = h_in + (size_t)d * B_SZ * H_SZ;

  float bval[2];
#pragma unroll
  for (int nt = 0; nt < 2; ++nt)
    bval[nt] = bias[d * G4 + n0 + wc * 32 + nt * 16 + r16];

  f32x4 acc[4][2];
#pragma unroll
  for (int mt = 0; mt < 4; ++mt)
#pragma unroll
    for (int nt = 0; nt < 2; ++nt) {
      f32x4 z = {0.f, 0.f, 0.f, 0.f};
      acc[mt][nt] = z;
    }

  const int rstg = tid >> 2;
  const int ostg = (tid & 3) * 8;

  // two NAMED in-flight register sets (static indexing only, rule #20)
  ushort8 pbhA, pblA, pvaA, pbhB, pblB, pvaB;
  auto loadA = [&](int kt) {
    const int k0 = kt * BKS;
    pbhA = *(const ushort8*)(Bh_mat + (size_t)(n0 + rstg) * H_SZ + k0 + ostg);
    pblA = *(const ushort8*)(Bl_mat + (size_t)(n0 + rstg) * H_SZ + k0 + ostg);
    pvaA = *(const ushort8*)(Ah + (size_t)(m0 + rstg) * H_SZ + k0 + ostg);
  };
  auto loadB = [&](int kt) {
    const int k0 = kt * BKS;
    pbhB = *(const ushort8*)(Bh_mat + (size_t)(n0 + rstg) * H_SZ + k0 + ostg);
    pblB = *(const ushort8*)(Bl_mat + (size_t)(n0 + rstg) * H_SZ + k0 + ostg);
    pvaB = *(const ushort8*)(Ah + (size_t)(m0 + rstg) * H_SZ + k0 + ostg);
  };
  auto storeA = [&](unsigned short* sA) {
    *(ushort8*)(sA + rstg * LDSKS + ostg)                  = pvaA;
    *(ushort8*)(sA + BM * LDSKS + rstg * LDSKS + ostg)     = pbhA;
    *(ushort8*)(sA + 2 * BM * LDSKS + rstg * LDSKS + ostg) = pblA;
  };
  auto storeB = [&](unsigned short* sA) {
    *(ushort8*)(sA + rstg * LDSKS + ostg)                  = pvaB;
    *(ushort8*)(sA + BM * LDSKS + rstg * LDSKS + ostg)     = pbhB;
    *(ushort8*)(sA + 2 * BM * LDSKS + rstg * LDSKS + ostg) = pblB;
  };
  auto compute = [&](const unsigned short* sA) {
    const unsigned short* sBh = sA + BM * LDSKS;
    const unsigned short* sBl = sBh + BM * LDSKS;
    bf16x8 af[4], bh[2];
#pragma unroll
    for (int mt = 0; mt < 4; ++mt)
      af[mt] = *(const bf16x8*)(sA + (wr * 64 + mt * 16 + r16) * LDSKS + q * 8);
#pragma unroll
    for (int nt = 0; nt < 2; ++nt)
      bh[nt] = *(const bf16x8*)(sBh + (wc * 32 + nt * 16 + r16) * LDSKS + q * 8);
#pragma unroll
    for (int mt = 0; mt < 4; ++mt)
#pragma unroll
      for (int nt = 0; nt < 2; ++nt)
        acc[mt][nt] = __builtin_amdgcn_mfma_f32_16x16x32_bf16(af[mt], bh[nt], acc[mt][nt], 0, 0, 0);
    bf16x8 bl[2];
#pragma unroll
    for (int nt = 0; nt < 2; ++nt)
      bl[nt] = *(const bf16x8*)(sBl + (wc * 32 + nt * 16 + r16) * LDSKS + q * 8);
#pragma unroll
    for (int mt = 0; mt < 4; ++mt)
#pragma unroll
      for (int nt = 0; nt < 2; ++nt)
        acc[mt][nt] = __builtin_amdgcn_mfma_f32_16x16x32_bf16(af[mt], bl[nt], acc[mt][nt], 0, 0, 0);
  };

  // epilogue-operand prefetch registers (cell layout; static indices only)
  float4 gpre[2][4];
  float  cpre[2][4];
  float  zpre[2][4];

  loadA(0);
  loadB(1);

  for (int kt2 = 0; kt2 < NITS; kt2 += 2) {
    // ---- even phase (data set A -> buf0) ----
    storeA(buf0);                 // counted vmcnt: loaded 2 iters ago
    bar_lgkm();                   // LDS visible; global loads stay in flight
    if (kt2 + 2 < NITS) loadA(kt2 + 2);
    compute(buf0);

    // ---- odd phase (data set B -> buf1) ----
    storeB(buf1);
    bar_lgkm();
    if (kt2 + 3 < NITS) loadB(kt2 + 3);
    if (kt2 == NITS - 6) {
      // Coalesced epilogue prefetch (float4 gx, contiguous c/zacc); drains at
      // the post-loop __syncthreads, ~5 iters of cover.
      const int jb = nb * 32;
#pragma unroll
      for (int cc = 0; cc < 2; ++cc)
#pragma unroll
        for (int it = 0; it < 4; ++it) {
          int cell = it * 512 + tid;
          int rl = cell >> 4, jq = cell & 15;
          int b = m0 + rl;
          int j = jb + cc * 16 + jq;
          gpre[cc][it] = *(const float4*)(gxcur + ((size_t)d * B_SZ + b) * G4 + (size_t)j * 4);
          cpre[cc][it] = c_st[((size_t)d * B_SZ + b) * H_SZ + j];
          if (LAYER == 1)
            zpre[cc][it] = zacc[(size_t)b * (2 * H_SZ) + d * H_SZ + j];
        }
    }
    compute(buf1);
  }
  __syncthreads();   // full drain (incl. epilogue prefetch) before gc reuse

  // ---- epilogue: 2 chunks of 64 gate-cols through gc[128][GP2] ----
  // C/D layout: col=lane&15, row=(lane>>4)*4+reg  [m89/m91 verified]
  // Chunk cc holds cols cc*64..cc*64+63 -> written by waves with wc>>1 == cc.
  const int jbase = nb * 32;
  const float ew = (LAYER == 1) ? emb_w[tcur] : 0.f;

#pragma unroll
  for (int cc = 0; cc < 2; ++cc) {
    if ((wc >> 1) == cc) {
#pragma unroll
      for (int mt = 0; mt < 4; ++mt)
#pragma unroll
        for (int nt = 0; nt < 2; ++nt)
#pragma unroll
          for (int r = 0; r < 4; ++r) {
            int ml = wr * 64 + mt * 16 + q * 4 + r;
            int nl = (wc & 1) * 32 + nt * 16 + r16;
            gc[ml * GP2 + nl] = acc[mt][nt][r] + bval[nt];
          }
    }
    __syncthreads();

#pragma unroll
    for (int it = 0; it < 4; ++it) {
      int cell = it * 512 + tid;
      int rl = cell >> 4, jq = cell & 15;
      int b = m0 + rl;
      int j = jbase + cc * 16 + jq;
      float4 g = *(const float4*)(&gc[rl * GP2 + jq * 4]);
      const float4 gx = gpre[cc][it];
      g.x += gx.x; g.y += gx.y; g.z += gx.z; g.w += gx.w;
      float si = sigmoidf_(g.x);
      float sf = sigmoidf_(g.y);
      float tg = tanhf_(g.z);
      float so = sigmoidf_(g.w);
      size_t cidx = ((size_t)d * B_SZ + b) * H_SZ + j;
      float cn = sf * cpre[cc][it] + si * tg;
      float hv = so * tanhf_(cn);
      c_st[cidx] = cn;
      h_out[cidx] = f2bf(hv);
      if (LAYER == 0) {
        seq_out[((size_t)tcur * B_SZ + b) * (2 * H_SZ) + d * H_SZ + j] = f2bf(hv);
      } else {
        zacc[(size_t)b * (2 * H_SZ) + d * H_SZ + j] = zpre[cc][it] + ew * hv;
      }
    }
    if (cc == 0) __syncthreads();
  }
}

// ============================================================
// GX ROLE: dense input-projection GEMM for step gx_step. BK=32, dbuf LDS,
// raw lgkm-only barriers, 2-deep named-register lookahead (rule #20).
// Unchanged from R3 (its wave grid is read-symmetric).
// L0: A = one-hot from xbits; L1: A = seq0[t].
// ============================================================
template <int LAYER>
__device__ void gx_role(char* smraw, int gid, int gx_step,
                        const unsigned int* __restrict__ xbits,     // [21,B,32]
                        const unsigned short* __restrict__ seq0,    // [T,B,2H]
                        const unsigned short* __restrict__ Bin,     // [2,G4,KIN]
                        float* __restrict__ gxnext) {               // [2,B,G4]
  if (gx_step >= TSTEPS) return;

  unsigned short* buf0 = (unsigned short*)smraw;
  unsigned short* buf1 = buf0 + GXBUF;

  const int tid  = threadIdx.x;
  const int lane = tid & 63;
  const int wave = tid >> 6;
  const int wr   = wave >> 1;
  const int wc   = wave & 1;
  const int q    = lane >> 4;
  const int r16  = lane & 15;

  const int xcd  = gid & 7;
  const int slot = gid >> 3;
  const int nb   = xcd * 2 + (slot & 1);
  const int mb   = (slot >> 1) & 15;
  const int d    = slot >> 5;
  const int tg   = d ? (TSTEPS - 1 - gx_step) : gx_step;
  const int n0   = nb * BN;
  const int m0   = mb * BM;

  const unsigned short* Bmat = Bin + (size_t)d * G4 * KIN;
  const unsigned char*  xrow = (const unsigned char*)xbits + ((size_t)tg * B_SZ) * (KIN / 8);
  const unsigned short* Asrc = seq0 + (size_t)tg * B_SZ * (2 * H_SZ);

  f32x4 acc[2][4];
#pragma unroll
  for (int mt = 0; mt < 2; ++mt)
#pragma unroll
    for (int nt = 0; nt < 4; ++nt) {
      f32x4 z = {0.f, 0.f, 0.f, 0.f};
      acc[mt][nt] = z;
    }

  const int rstg = tid >> 2;          // 0..127
  const int ostg = (tid & 3) * 8;

  ushort8 pbA, paA, pbB, paB;
  unsigned int bvA, bvB;
  auto loadA = [&](int kt) {
    const int k0 = kt * BKS;
    pbA = *(const ushort8*)(Bmat + (size_t)(n0 + rstg) * KIN + k0 + ostg);
    if (LAYER == 0) {
      bvA = xrow[(size_t)(m0 + rstg) * (KIN / 8) + (k0 + ostg) / 8];
    } else {
      paA = *(const ushort8*)(Asrc + (size_t)(m0 + rstg) * (2 * H_SZ) + k0 + ostg);
    }
  };
  auto loadB = [&](int kt) {
    const int k0 = kt * BKS;
    pbB = *(const ushort8*)(Bmat + (size_t)(n0 + rstg) * KIN + k0 + ostg);
    if (LAYER == 0) {
      bvB = xrow[(size_t)(m0 + rstg) * (KIN / 8) + (k0 + ostg) / 8];
    } else {
      paB = *(const ushort8*)(Asrc + (size_t)(m0 + rstg) * (2 * H_SZ) + k0 + ostg);
    }
  };
  auto expand = [&](unsigned int bv, unsigned short* sA) {
    unsigned int pk[4];
#pragma unroll
    for (int e = 0; e < 4; ++e) {
      pk[e] = (((bv >> (2 * e)) & 1u) ? 0x3F80u : 0u)
            | (((bv >> (2 * e + 1)) & 1u) ? 0x3F800000u : 0u);
    }
    *(uint4*)(sA + rstg * LDSKS + ostg) = make_uint4(pk[0], pk[1], pk[2], pk[3]);
  };
  auto storeA = [&](unsigned short* sA) {
    unsigned short* sB = sA + BM * LDSKS;
    if (LAYER == 0) expand(bvA, sA);
    else            *(ushort8*)(sA + rstg * LDSKS + ostg) = paA;
    *(ushort8*)(sB + rstg * LDSKS + ostg) = pbA;
  };
  auto storeB = [&](unsigned short* sA) {
    unsigned short* sB = sA + BM * LDSKS;
    if (LAYER == 0) expand(bvB, sA);
    else            *(ushort8*)(sA + rstg * LDSKS + ostg) = paB;
    *(ushort8*)(sB + rstg * LDSKS + ostg) = pbB;
  };
  auto compute = [&](const unsigned short* sA) {
    const unsigned short* sB = sA + BM * LDSKS;
    bf16x8 af[2], bh[4];
#pragma unroll
    for (int mt = 0; mt < 2; ++mt)
      af[mt] = *(const bf16x8*)(sA + (wr * 32 + mt * 16 + r16) * LDSKS + q * 8);
#pragma unroll
    for (int nt = 0; nt < 4; ++nt)
      bh[nt] = *(const bf16x8*)(sB + (wc * 64 + nt * 16 + r16) * LDSKS + q * 8);
#pragma unroll
    for (int mt = 0; mt < 2; ++mt)
#pragma unroll
      for (int nt = 0; nt < 4; ++nt)
        acc[mt][nt] = __builtin_amdgcn_mfma_f32_16x16x32_bf16(af[mt], bh[nt], acc[mt][nt], 0, 0, 0);
  };

  loadA(0);
  loadB(1);

  for (int kt2 = 0; kt2 < NITG; kt2 += 2) {
    storeA(buf0);
    bar_lgkm();
    if (kt2 + 2 < NITG) loadA(kt2 + 2);
    compute(buf0);

    storeB(buf1);
    bar_lgkm();
    if (kt2 + 3 < NITG) loadB(kt2 + 3);
    compute(buf1);
  }

  // write gx (C/D layout: col=lane&15, row=quad*4+reg)
#pragma unroll
  for (int mt = 0; mt < 2; ++mt)
#pragma unroll
    for (int nt = 0; nt < 4; ++nt)
#pragma unroll
      for (int r = 0; r < 4; ++r) {
        int row = m0 + wr * 32 + mt * 16 + q * 4 + r;
        int col = n0 + wc * 64 + nt * 16 + r16;
        gxnext[((size_t)d * B_SZ + row) * G4 + col] = acc[mt][nt][r];
      }
}

// ============================================================ fused launcher
// (512,4): 4 waves/EU -> 128-VGPR budget, 2 blocks/CU (matches 61440 B LDS).
template <int LAYER>
__global__ __launch_bounds__(512, 4)
void fused_kernel(const unsigned int* __restrict__ xbits,
                  const unsigned short* __restrict__ seq0,
                  const unsigned short* __restrict__ Bin,
                  const unsigned short* __restrict__ Bhrec,
                  const unsigned short* __restrict__ Blrec,
                  const float* __restrict__ bias,
                  const unsigned short* __restrict__ h_in,
                  unsigned short* __restrict__ h_out,
                  float* __restrict__ c_st,
                  unsigned short* __restrict__ seq_out,
                  float* __restrict__ zacc,
                  const float* __restrict__ emb_w,
                  const float* __restrict__ gxcur,
                  float* __restrict__ gxnext,
                  int step, int gx_step) {
  extern __shared__ char smraw[];
  const int bid = blockIdx.x;
  if ((bid & 1) == 0) {
    step_role<LAYER>(smraw, bid >> 1, step, Bhrec, Blrec, bias, h_in, h_out,
                     c_st, seq_out, zacc, emb_w, gxcur);
  } else {
    gx_role<LAYER>(smraw, bid >> 1, gx_step, xbits, seq0, Bin, gxnext);
  }
}

template <int LAYER>
__global__ __launch_bounds__(512, 4)
void gx_only_kernel(const unsigned int* __restrict__ xbits,
                    const unsigned short* __restrict__ seq0,
                    const unsigned short* __restrict__ Bin,
                    float* __restrict__ gxnext, int gx_step) {
  extern __shared__ char smraw[];
  gx_role<LAYER>(smraw, blockIdx.x, gx_step, xbits, seq0, Bin, gxnext);
}

// ============================================================ final
__global__ __launch_bounds__(256)
void final_kernel(const float* __restrict__ zacc,
                  const float* __restrict__ emb_b,
                  const float* __restrict__ fc_w,
                  const float* __restrict__ fc_b,
                  float* __restrict__ out) {
  const int b = blockIdx.x;
  const int tid = threadIdx.x;
  const int c0 = tid * 4;

  const float zb = emb_b[0];
  const float4 z4 = *(const float4*)(zacc + (size_t)b * (2 * H_SZ) + c0);
  float z0 = z4.x + zb, z1 = z4.y + zb, z2 = z4.z + zb, z3 = z4.w + zb;

  float part[NCLS];
#pragma unroll
  for (int nc = 0; nc < NCLS; ++nc) {
    const float4 f = *(const float4*)(fc_w + (size_t)nc * (2 * H_SZ) + c0);
    part[nc] = z0 * f.x + z1 * f.y + z2 * f.z + z3 * f.w;
  }
#pragma unroll
  for (int nc = 0; nc < NCLS; ++nc)
#pragma unroll
    for (int off2 = 32; off2 > 0; off2 >>= 1)
      part[nc] += __shfl_down(part[nc], off2);

  __shared__ float red[4][NCLS];
  if ((tid & 63) == 0) {
#pragma unroll
    for (int nc = 0; nc < NCLS; ++nc) red[tid >> 6][nc] = part[nc];
  }
  __syncthreads();
  if (tid < NCLS) {
    float s = red[0][tid] + red[1][tid] + red[2][tid] + red[3][tid] + fc_b[tid];
    out[b * NCLS + tid] = s;
  }
}

// ============================================================
extern "C" void kernel_launch(void* const* d_in, const int* in_sizes, int n_in,
                              void* d_out, int out_size, void* d_ws, size_t ws_size,
                              hipStream_t stream) {
  (void)in_sizes; (void)n_in; (void)out_size; (void)ws_size;

  const int*   x     = (const int*)d_in[0];
  const float* w_ih0 = (const float*)d_in[1];
  const float* w_hh0 = (const float*)d_in[2];
  const float* b_ih0 = (const float*)d_in[3];
  const float* b_hh0 = (const float*)d_in[4];
  const float* w_ih1 = (const float*)d_in[5];
  const float* w_hh1 = (const float*)d_in[6];
  const float* b_ih1 = (const float*)d_in[7];
  const float* b_hh1 = (const float*)d_in[8];
  const float* emb_w = (const float*)d_in[9];
  const float* emb_b = (const float*)d_in[10];
  const float* fc_w  = (const float*)d_in[11];
  const float* fc_b  = (const float*)d_in[12];

  // -------- workspace (~211 MB) --------
  char* ws = (char*)d_ws;
  size_t off = 0;
  auto alloc = [&](size_t bytes) -> void* {
    void* p = ws + off;
    off += (bytes + 255) & ~(size_t)255;
    return p;
  };
  const size_t bin_b  = (size_t)2 * G4 * KIN * 2;               // 8.39 MB
  const size_t brec_b = (size_t)2 * G4 * H_SZ * 2;              // 4.19 MB
  const size_t xb_b   = (size_t)TSTEPS * B_SZ * 32 * 4;         // 5.50 MB
  const size_t h_b    = (size_t)2 * B_SZ * H_SZ * 2;            // 4.19 MB
  const size_t c_b    = (size_t)2 * B_SZ * H_SZ * 4;            // 8.39 MB
  const size_t gx_b   = (size_t)2 * B_SZ * G4 * 4;              // 33.55 MB
  const size_t seq_b  = (size_t)TSTEPS * B_SZ * (2 * H_SZ) * 2; // 88.08 MB
  const size_t z_b    = (size_t)B_SZ * (2 * H_SZ) * 4;          // 8.39 MB

  unsigned short* Bin0  = (unsigned short*)alloc(bin_b);   // L0-only; zacc aliases
  unsigned short* Bin1  = (unsigned short*)alloc(bin_b);
  unsigned short* Bh0   = (unsigned short*)alloc(brec_b);
  unsigned short* Bl0   = (unsigned short*)alloc(brec_b);
  unsigned short* Bh1   = (unsigned short*)alloc(brec_b);
  unsigned short* Bl1   = (unsigned short*)alloc(brec_b);
  float*          bias0 = (float*)alloc((size_t)2 * G4 * 4);
  float*          bias1 = (float*)alloc((size_t)2 * G4 * 4);
  unsigned int*   xbits = (unsigned int*)alloc(xb_b);
  unsigned short* hA    = (unsigned short*)alloc(h_b);
  unsigned short* hB    = (unsigned short*)alloc(h_b);
  float*          cst   = (float*)alloc(c_b);
  float*          gxA   = (float*)alloc(gx_b);
  float*          gxB   = (float*)alloc(gx_b);
  unsigned short* seq0  = (unsigned short*)alloc(seq_b);
  float*          zacc  = (float*)Bin0;   // Bin0 (8.39 MB) dead after layer 0; z_b == bin_b

  // -------- prep --------
  {
    size_t ti = (size_t)2 * G4 * KIN;
    prep_in0_kernel<<<(int)((ti + 255) / 256), 256, 0, stream>>>(w_ih0, Bin0);
    prep_in1_kernel<<<(int)((ti + 255) / 256), 256, 0, stream>>>(w_ih1, Bin1);
    size_t tr = (size_t)2 * G4 * H_SZ;
    prep_rec_kernel<<<(int)((tr + 255) / 256), 256, 0, stream>>>(w_hh0, Bh0, Bl0);
    prep_rec_kernel<<<(int)((tr + 255) / 256), 256, 0, stream>>>(w_hh1, Bh1, Bl1);
    prep_b_kernel<<<16, 256, 0, stream>>>(b_ih0, b_hh0, b_ih1, b_hh1, bias0, bias1);
    prep_x_kernel<<<(B_SZ * 32 + 255) / 256, 256, 0, stream>>>(x, xbits);
  }

  // -------- layer 0 --------
  hipMemsetAsync(hA, 0, h_b, stream);
  hipMemsetAsync(cst, 0, c_b, stream);
  gx_only_kernel<0><<<512, 512, SMEM_BYTES, stream>>>(xbits, nullptr, Bin0, gxA, 0);
  for (int s = 0; s < TSTEPS; ++s) {
    const unsigned short* hin  = (s & 1) ? hB : hA;
    unsigned short*       hout = (s & 1) ? hA : hB;
    float* cur = (s & 1) ? gxB : gxA;
    float* nxt = (s & 1) ? gxA : gxB;
    fused_kernel<0><<<1024, 512, SMEM_BYTES, stream>>>(
        xbits, nullptr, Bin0, Bh0, Bl0, bias0, hin, hout, cst,
        seq0, nullptr, nullptr, cur, nxt, s, s + 1);
  }

  // -------- layer 1 --------
  hipMemsetAsync(hA, 0, h_b, stream);
  hipMemsetAsync(cst, 0, c_b, stream);
  hipMemsetAsync(zacc, 0, z_b, stream);
  gx_only_kernel<1><<<512, 512, SMEM_BYTES, stream>>>(nullptr, seq0, Bin1, gxA, 0);
  for (int s = 0; s < TSTEPS; ++s) {
    const unsigned short* hin  = (s & 1) ? hB : hA;
    unsigned short*       hout = (s & 1) ? hA : hB;
    float* cur = (s & 1) ? gxB : gxA;
    float* nxt = (s & 1) ? gxA : gxB;
    fused_kernel<1><<<1024, 512, SMEM_BYTES, stream>>>(
        nullptr, seq0, Bin1, Bh1, Bl1, bias1, hin, hout, cst,
        nullptr, zacc, emb_w, cur, nxt, s, s + 1);
  }

  // -------- fc --------
  final_kernel<<<B_SZ, 256, 0, stream>>>(zacc, emb_b, fc_w, fc_b, (float*)d_out);
}

// Round 6
// 2176.325 us; speedup vs baseline: 2.0716x; 1.2624x over previous
//
#include <hip/hip_runtime.h>
#include <hip/hip_bf16.h>
#include <cstdint>
#include <cstddef>

// ---------------- model dims ----------------
#define B_SZ    2048
#define H_SZ    512
#define G4      2048      // 4*H
#define TSTEPS  21
#define MAXLEN  1000
#define KIN     1024      // input-K (L0 one-hot padded 1000->1024; L1 2H=1024)
#define NCLS    10

// ---------------- tiles ----------------
#define BM    128
#define BN    128
#define BKS   32          // K-tile (gx: K=1024 -> 32 it; step: K=512 -> 16 dual it)
#define LDSKS 40          // LDS K-stride (80 B, 16B-aligned)
#define NITS  16
#define NITG  32
#define GP2   68          // gc f32 stride: all float4 16B-aligned, 2-way banks max
#define STEPBUF (3 * BM * LDSKS)   // shorts per step staging buffer (A,Bh,Bl) = 15360
#define GXBUF   (2 * BM * LDSKS)   // shorts per gx staging buffer (A,B) = 10240
// step dbuf 2*30720=61440 B; gx dbuf 2*20480=40960 B (same region); gc 34816 B
#define SMEM_BYTES 61440  // 2 blocks/CU

typedef short bf16x8 __attribute__((ext_vector_type(8)));
typedef float f32x4  __attribute__((ext_vector_type(4)));
typedef unsigned short ushort8 __attribute__((ext_vector_type(8)));

__device__ __forceinline__ unsigned short f2bf(float f) {
  __hip_bfloat16 h = __float2bfloat16(f);
  unsigned short u; __builtin_memcpy(&u, &h, sizeof(u)); return u;
}
__device__ __forceinline__ float bf2f(unsigned short u) {
  __hip_bfloat16 h; __builtin_memcpy(&h, &u, sizeof(h)); return __bfloat162float(h);
}
__device__ __forceinline__ float sigmoidf_(float x) {
  x = fminf(fmaxf(x, -30.f), 30.f);
  return 1.f / (1.f + __expf(-x));
}
__device__ __forceinline__ float tanhf_(float x) {
  float xc = fminf(fmaxf(x, -15.f), 15.f);
  float e = __expf(2.f * xc);
  return (e - 1.f) / (e + 1.f);
}
// Raw barrier: LDS-visibility only (lgkmcnt), NO vmcnt drain -> global
// prefetch loads stay in flight across barriers (T4 counted-wait mechanism).
// sched_barrier(0) guards against hoisting past the asm (rule #18).
__device__ __forceinline__ void bar_lgkm() {
  asm volatile("s_waitcnt lgkmcnt(0)" ::: "memory");
  __builtin_amdgcn_s_barrier();
  __builtin_amdgcn_sched_barrier(0);
}
// gate permutation p = 4*j + type  <->  orig row type*512 + j (i,f,g,o)
__device__ __forceinline__ int rbase_of(int p) { return (p & 3) * H_SZ + (p >> 2); }

// ============================================================ prep kernels
__global__ void prep_rec_kernel(const float* __restrict__ w_hh,
                                unsigned short* __restrict__ Bhi,
                                unsigned short* __restrict__ Blo) {
  size_t idx = (size_t)blockIdx.x * blockDim.x + threadIdx.x;
  const size_t total = (size_t)2 * G4 * H_SZ;
  if (idx >= total) return;
  int k  = (int)(idx % H_SZ);
  size_t rowidx = idx / H_SZ;
  int p  = (int)(rowidx % G4);
  int dd = (int)(rowidx / G4);
  float w = w_hh[((size_t)dd * G4 + rbase_of(p)) * H_SZ + k];
  unsigned short h = f2bf(w);
  Bhi[idx] = h;
  Blo[idx] = f2bf(w - bf2f(h));
}

__global__ void prep_in0_kernel(const float* __restrict__ w_ih0,
                                unsigned short* __restrict__ Bin0) {  // [2,G4,KIN]
  size_t idx = (size_t)blockIdx.x * blockDim.x + threadIdx.x;
  const size_t total = (size_t)2 * G4 * KIN;
  if (idx >= total) return;
  int k  = (int)(idx % KIN);
  size_t rowidx = idx / KIN;
  int p  = (int)(rowidx % G4);
  int dd = (int)(rowidx / G4);
  float v = (k < MAXLEN) ? w_ih0[((size_t)dd * G4 + rbase_of(p)) * MAXLEN + k] : 0.f;
  Bin0[idx] = f2bf(v);
}

__global__ void prep_in1_kernel(const float* __restrict__ w_ih1,
                                unsigned short* __restrict__ Bin1) {  // [2,G4,KIN]
  size_t idx = (size_t)blockIdx.x * blockDim.x + threadIdx.x;
  const size_t total = (size_t)2 * G4 * KIN;
  if (idx >= total) return;
  int k  = (int)(idx % KIN);
  size_t rowidx = idx / KIN;
  int p  = (int)(rowidx % G4);
  int dd = (int)(rowidx / G4);
  Bin1[idx] = f2bf(w_ih1[((size_t)dd * G4 + rbase_of(p)) * KIN + k]);
}

__global__ void prep_b_kernel(const float* __restrict__ b_ih0,
                              const float* __restrict__ b_hh0,
                              const float* __restrict__ b_ih1,
                              const float* __restrict__ b_hh1,
                              float* __restrict__ bias0,
                              float* __restrict__ bias1) {
  int idx = blockIdx.x * blockDim.x + threadIdx.x;
  if (idx >= 2 * G4) return;
  int p  = idx % G4;
  int dd = idx / G4;
  int src = dd * G4 + rbase_of(p);
  bias0[idx] = b_ih0[src] + b_hh0[src];
  bias1[idx] = b_ih1[src] + b_hh1[src];
}

// one-hot bitmasks: bits[t][b][w] bit j set iff x[b, 32w+j]==t (pos<MAXLEN)
__global__ void prep_x_kernel(const int* __restrict__ x,
                              unsigned int* __restrict__ bits) {
  int idx = blockIdx.x * blockDim.x + threadIdx.x;
  if (idx >= B_SZ * 32) return;
  int b = idx >> 5;
  int w = idx & 31;
  const int* xr = x + (size_t)b * MAXLEN + w * 32;
  int xv[32];
#pragma unroll
  for (int j = 0; j < 32; ++j) {
    int k = w * 32 + j;
    xv[j] = (k < MAXLEN) ? xr[j] : -1;
  }
#pragma unroll
  for (int t = 0; t < TSTEPS; ++t) {
    unsigned int m = 0;
#pragma unroll
    for (int j = 0; j < 32; ++j)
      m |= (xv[j] == t) ? (1u << j) : 0u;
    bits[((size_t)t * B_SZ + b) * 32 + w] = m;
  }
}

// ============================================================
// MERGED KERNEL: per (d, mb, nb) block, compute the FULL gate tile for the
// current step in one accumulator:
//   phase 1 (gx): acc += W_ih . x_t     (K=1024, 32 iters, A from xbits/seq)
//   phase 2 (st): acc += W_hh_hi/lo . h (K=512, 16 dual iters)
//   epilogue: gates = acc + bias -> LSTM cell -> h_out/c_st/seq/zacc.
// No gx pipeline buffer: saves 67 MB f32 HBM round-trip per dispatch and
// halves the grid (512 blocks -> single residency round).
// Pipeline: dbuf LDS, raw lgkm-only barriers, 2-deep NAMED-register
// lookahead (rule #20); step prologue loads issued under last gx iters.
// ============================================================
template <int LAYER>
__global__ __launch_bounds__(512, 4)
void fused_kernel(const unsigned int* __restrict__ xbits,     // [21,B,32]  (L0)
                  const unsigned short* __restrict__ seq_in,  // [T,B,2H]   (L1)
                  const unsigned short* __restrict__ Bin,     // [2,G4,KIN]
                  const unsigned short* __restrict__ Bhrec,   // [2,G4,512]
                  const unsigned short* __restrict__ Blrec,   // [2,G4,512]
                  const float* __restrict__ bias,             // [2,G4]
                  const unsigned short* __restrict__ h_in,    // [2,B,H]
                  unsigned short* __restrict__ h_out,
                  float* __restrict__ c_st,                   // [2,B,H]
                  unsigned short* __restrict__ seq_out,       // [T,B,2H] (L0)
                  float* __restrict__ zacc,                   // [B,2H]   (L1)
                  const float* __restrict__ emb_w,            // [21]     (L1)
                  int step) {
  extern __shared__ char smraw[];
  unsigned short* buf0s = (unsigned short*)smraw;            // step dbuf
  unsigned short* buf1s = buf0s + STEPBUF;
  unsigned short* buf0g = (unsigned short*)smraw;            // gx dbuf (same region)
  unsigned short* buf1g = buf0g + GXBUF;
  float*          gc    = (float*)smraw;                     // epilogue [128][GP2]

  const int tid  = threadIdx.x;
  const int lane = tid & 63;
  const int wave = tid >> 6;                       // 0..7
  const int wr   = wave >> 2;                      // 0..1  (M)
  const int wc   = wave & 3;                       // 0..3  (N)
  const int q    = lane >> 4;
  const int r16  = lane & 15;

  const int sid  = blockIdx.x;                     // 0..511
  const int xcd  = sid & 7;
  const int slot = sid >> 3;
  const int nb   = xcd * 2 + (slot & 1);
  const int mb   = (slot >> 1) & 15;
  const int d    = slot >> 5;
  const int tcur = d ? (TSTEPS - 1 - step) : step;
  const int n0   = nb * BN;
  const int m0   = mb * BM;

  const unsigned short* Bh_mat = Bhrec + (size_t)d * G4 * H_SZ;
  const unsigned short* Bl_mat = Blrec + (size_t)d * G4 * H_SZ;
  const unsigned short* Ah     = h_in + (size_t)d * B_SZ * H_SZ;
  const unsigned short* Bmat   = Bin + (size_t)d * G4 * KIN;
  const unsigned char*  xrow   = (const unsigned char*)xbits + ((size_t)tcur * B_SZ) * (KIN / 8);
  const unsigned short* Asrc   = seq_in + (size_t)tcur * B_SZ * (2 * H_SZ);

  float bval[2];
#pragma unroll
  for (int nt = 0; nt < 2; ++nt)
    bval[nt] = bias[d * G4 + n0 + wc * 32 + nt * 16 + r16];

  f32x4 acc[4][2];
#pragma unroll
  for (int mt = 0; mt < 4; ++mt)
#pragma unroll
    for (int nt = 0; nt < 2; ++nt) {
      f32x4 z = {0.f, 0.f, 0.f, 0.f};
      acc[mt][nt] = z;
    }

  const int rstg = tid >> 2;          // 0..127
  const int ostg = (tid & 3) * 8;

  // -------- gx-phase staging (NAMED sets, rule #20) --------
  ushort8 pbA, paA, pbB, paB;
  unsigned int bvA, bvB;
  auto gloadA = [&](int kt) {
    const int k0 = kt * BKS;
    pbA = *(const ushort8*)(Bmat + (size_t)(n0 + rstg) * KIN + k0 + ostg);
    if (LAYER == 0) {
      bvA = xrow[(size_t)(m0 + rstg) * (KIN / 8) + (k0 + ostg) / 8];
    } else {
      paA = *(const ushort8*)(Asrc + (size_t)(m0 + rstg) * (2 * H_SZ) + k0 + ostg);
    }
  };
  auto gloadB = [&](int kt) {
    const int k0 = kt * BKS;
    pbB = *(const ushort8*)(Bmat + (size_t)(n0 + rstg) * KIN + k0 + ostg);
    if (LAYER == 0) {
      bvB = xrow[(size_t)(m0 + rstg) * (KIN / 8) + (k0 + ostg) / 8];
    } else {
      paB = *(const ushort8*)(Asrc + (size_t)(m0 + rstg) * (2 * H_SZ) + k0 + ostg);
    }
  };
  auto expand = [&](unsigned int bv, unsigned short* dst) {
    unsigned int pk[4];
#pragma unroll
    for (int e = 0; e < 4; ++e) {
      pk[e] = (((bv >> (2 * e)) & 1u) ? 0x3F80u : 0u)
            | (((bv >> (2 * e + 1)) & 1u) ? 0x3F800000u : 0u);
    }
    *(uint4*)dst = make_uint4(pk[0], pk[1], pk[2], pk[3]);
  };
  auto gstoreA = [&](unsigned short* sA) {
    unsigned short* sB = sA + BM * LDSKS;
    if (LAYER == 0) expand(bvA, sA + rstg * LDSKS + ostg);
    else            *(ushort8*)(sA + rstg * LDSKS + ostg) = paA;
    *(ushort8*)(sB + rstg * LDSKS + ostg) = pbA;
  };
  auto gstoreB = [&](unsigned short* sA) {
    unsigned short* sB = sA + BM * LDSKS;
    if (LAYER == 0) expand(bvB, sA + rstg * LDSKS + ostg);
    else            *(ushort8*)(sA + rstg * LDSKS + ostg) = paB;
    *(ushort8*)(sB + rstg * LDSKS + ostg) = pbB;
  };
  auto gcompute = [&](const unsigned short* sA) {
    const unsigned short* sB = sA + BM * LDSKS;
    bf16x8 af[4], bh[2];
#pragma unroll
    for (int mt = 0; mt < 4; ++mt)
      af[mt] = *(const bf16x8*)(sA + (wr * 64 + mt * 16 + r16) * LDSKS + q * 8);
#pragma unroll
    for (int nt = 0; nt < 2; ++nt)
      bh[nt] = *(const bf16x8*)(sB + (wc * 32 + nt * 16 + r16) * LDSKS + q * 8);
#pragma unroll
    for (int mt = 0; mt < 4; ++mt)
#pragma unroll
      for (int nt = 0; nt < 2; ++nt)
        acc[mt][nt] = __builtin_amdgcn_mfma_f32_16x16x32_bf16(af[mt], bh[nt], acc[mt][nt], 0, 0, 0);
  };

  // -------- step-phase staging (NAMED sets) --------
  ushort8 pbhA, pblA, pvaA, pbhB, pblB, pvaB;
  auto sloadA = [&](int kt) {
    const int k0 = kt * BKS;
    pbhA = *(const ushort8*)(Bh_mat + (size_t)(n0 + rstg) * H_SZ + k0 + ostg);
    pblA = *(const ushort8*)(Bl_mat + (size_t)(n0 + rstg) * H_SZ + k0 + ostg);
    pvaA = *(const ushort8*)(Ah + (size_t)(m0 + rstg) * H_SZ + k0 + ostg);
  };
  auto sloadB = [&](int kt) {
    const int k0 = kt * BKS;
    pbhB = *(const ushort8*)(Bh_mat + (size_t)(n0 + rstg) * H_SZ + k0 + ostg);
    pblB = *(const ushort8*)(Bl_mat + (size_t)(n0 + rstg) * H_SZ + k0 + ostg);
    pvaB = *(const ushort8*)(Ah + (size_t)(m0 + rstg) * H_SZ + k0 + ostg);
  };
  auto sstoreA = [&](unsigned short* sA) {
    *(ushort8*)(sA + rstg * LDSKS + ostg)                  = pvaA;
    *(ushort8*)(sA + BM * LDSKS + rstg * LDSKS + ostg)     = pbhA;
    *(ushort8*)(sA + 2 * BM * LDSKS + rstg * LDSKS + ostg) = pblA;
  };
  auto sstoreB = [&](unsigned short* sA) {
    *(ushort8*)(sA + rstg * LDSKS + ostg)                  = pvaB;
    *(ushort8*)(sA + BM * LDSKS + rstg * LDSKS + ostg)     = pbhB;
    *(ushort8*)(sA + 2 * BM * LDSKS + rstg * LDSKS + ostg) = pblB;
  };
  auto scompute = [&](const unsigned short* sA) {
    const unsigned short* sBh = sA + BM * LDSKS;
    const unsigned short* sBl = sBh + BM * LDSKS;
    bf16x8 af[4], bh[2];
#pragma unroll
    for (int mt = 0; mt < 4; ++mt)
      af[mt] = *(const bf16x8*)(sA + (wr * 64 + mt * 16 + r16) * LDSKS + q * 8);
#pragma unroll
    for (int nt = 0; nt < 2; ++nt)
      bh[nt] = *(const bf16x8*)(sBh + (wc * 32 + nt * 16 + r16) * LDSKS + q * 8);
#pragma unroll
    for (int mt = 0; mt < 4; ++mt)
#pragma unroll
      for (int nt = 0; nt < 2; ++nt)
        acc[mt][nt] = __builtin_amdgcn_mfma_f32_16x16x32_bf16(af[mt], bh[nt], acc[mt][nt], 0, 0, 0);
    bf16x8 bl[2];
#pragma unroll
    for (int nt = 0; nt < 2; ++nt)
      bl[nt] = *(const bf16x8*)(sBl + (wc * 32 + nt * 16 + r16) * LDSKS + q * 8);
#pragma unroll
    for (int mt = 0; mt < 4; ++mt)
#pragma unroll
      for (int nt = 0; nt < 2; ++nt)
        acc[mt][nt] = __builtin_amdgcn_mfma_f32_16x16x32_bf16(af[mt], bl[nt], acc[mt][nt], 0, 0, 0);
  };

  // epilogue-operand prefetch registers (cell layout; static indices only)
  float cpre[2][4];
  float zpre[2][4];

  // ================= phase 1: gx (K = KIN) =================
  gloadA(0);
  gloadB(1);
  for (int kt2 = 0; kt2 < NITG; kt2 += 2) {
    gstoreA(buf0g);
    bar_lgkm();
    if (kt2 + 2 < NITG) gloadA(kt2 + 2); else sloadA(0);   // step prologue
    gcompute(buf0g);

    gstoreB(buf1g);
    bar_lgkm();
    if (kt2 + 3 < NITG) gloadB(kt2 + 3); else sloadB(1);   // under last gx iters
    gcompute(buf1g);
  }
  bar_lgkm();   // phase fence: all gx LDS reads done before step stores overwrite

  // ================= phase 2: recurrent (K = 512, hi+lo) =================
  for (int kt2 = 0; kt2 < NITS; kt2 += 2) {
    sstoreA(buf0s);
    bar_lgkm();
    if (kt2 + 2 < NITS) sloadA(kt2 + 2);
    scompute(buf0s);

    sstoreB(buf1s);
    bar_lgkm();
    if (kt2 + 3 < NITS) sloadB(kt2 + 3);
    if (kt2 == NITS - 6) {
      // Coalesced epilogue prefetch; drains at the post-loop __syncthreads,
      // ~5 iters of cover.
      const int jb = nb * 32;
#pragma unroll
      for (int cc = 0; cc < 2; ++cc)
#pragma unroll
        for (int it = 0; it < 4; ++it) {
          int cell = it * 512 + tid;
          int rl = cell >> 4, jq = cell & 15;
          int b = m0 + rl;
          int j = jb + cc * 16 + jq;
          cpre[cc][it] = c_st[((size_t)d * B_SZ + b) * H_SZ + j];
          if (LAYER == 1)
            zpre[cc][it] = zacc[(size_t)b * (2 * H_SZ) + d * H_SZ + j];
        }
    }
    scompute(buf1s);
  }
  __syncthreads();   // full drain (incl. epilogue prefetch) before gc reuse

  // ---- epilogue: 2 chunks of 64 gate-cols through gc[128][GP2] ----
  // C/D layout: col=lane&15, row=(lane>>4)*4+reg  [m89/m91 verified]
  // Chunk cc holds cols cc*64..cc*64+63 -> written by waves with wc>>1 == cc.
  const int jbase = nb * 32;
  const float ew = (LAYER == 1) ? emb_w[tcur] : 0.f;

#pragma unroll
  for (int cc = 0; cc < 2; ++cc) {
    if ((wc >> 1) == cc) {
#pragma unroll
      for (int mt = 0; mt < 4; ++mt)
#pragma unroll
        for (int nt = 0; nt < 2; ++nt)
#pragma unroll
          for (int r = 0; r < 4; ++r) {
            int ml = wr * 64 + mt * 16 + q * 4 + r;
            int nl = (wc & 1) * 32 + nt * 16 + r16;
            gc[ml * GP2 + nl] = acc[mt][nt][r] + bval[nt];
          }
    }
    __syncthreads();

#pragma unroll
    for (int it = 0; it < 4; ++it) {
      int cell = it * 512 + tid;
      int rl = cell >> 4, jq = cell & 15;
      int b = m0 + rl;
      int j = jbase + cc * 16 + jq;
      float4 g = *(const float4*)(&gc[rl * GP2 + jq * 4]);
      float si = sigmoidf_(g.x);
      float sf = sigmoidf_(g.y);
      float tg = tanhf_(g.z);
      float so = sigmoidf_(g.w);
      size_t cidx = ((size_t)d * B_SZ + b) * H_SZ + j;
      float cn = sf * cpre[cc][it] + si * tg;
      float hv = so * tanhf_(cn);
      c_st[cidx] = cn;
      h_out[cidx] = f2bf(hv);
      if (LAYER == 0) {
        seq_out[((size_t)tcur * B_SZ + b) * (2 * H_SZ) + d * H_SZ + j] = f2bf(hv);
      } else {
        zacc[(size_t)b * (2 * H_SZ) + d * H_SZ + j] = zpre[cc][it] + ew * hv;
      }
    }
    if (cc == 0) __syncthreads();
  }
}

// ============================================================ final
__global__ __launch_bounds__(256)
void final_kernel(const float* __restrict__ zacc,
                  const float* __restrict__ emb_b,
                  const float* __restrict__ fc_w,
                  const float* __restrict__ fc_b,
                  float* __restrict__ out) {
  const int b = blockIdx.x;
  const int tid = threadIdx.x;
  const int c0 = tid * 4;

  const float zb = emb_b[0];
  const float4 z4 = *(const float4*)(zacc + (size_t)b * (2 * H_SZ) + c0);
  float z0 = z4.x + zb, z1 = z4.y + zb, z2 = z4.z + zb, z3 = z4.w + zb;

  float part[NCLS];
#pragma unroll
  for (int nc = 0; nc < NCLS; ++nc) {
    const float4 f = *(const float4*)(fc_w + (size_t)nc * (2 * H_SZ) + c0);
    part[nc] = z0 * f.x + z1 * f.y + z2 * f.z + z3 * f.w;
  }
#pragma unroll
  for (int nc = 0; nc < NCLS; ++nc)
#pragma unroll
    for (int off2 = 32; off2 > 0; off2 >>= 1)
      part[nc] += __shfl_down(part[nc], off2);

  __shared__ float red[4][NCLS];
  if ((tid & 63) == 0) {
#pragma unroll
    for (int nc = 0; nc < NCLS; ++nc) red[tid >> 6][nc] = part[nc];
  }
  __syncthreads();
  if (tid < NCLS) {
    float s = red[0][tid] + red[1][tid] + red[2][tid] + red[3][tid] + fc_b[tid];
    out[b * NCLS + tid] = s;
  }
}

// ============================================================
extern "C" void kernel_launch(void* const* d_in, const int* in_sizes, int n_in,
                              void* d_out, int out_size, void* d_ws, size_t ws_size,
                              hipStream_t stream) {
  (void)in_sizes; (void)n_in; (void)out_size; (void)ws_size;

  const int*   x     = (const int*)d_in[0];
  const float* w_ih0 = (const float*)d_in[1];
  const float* w_hh0 = (const float*)d_in[2];
  const float* b_ih0 = (const float*)d_in[3];
  const float* b_hh0 = (const float*)d_in[4];
  const float* w_ih1 = (const float*)d_in[5];
  const float* w_hh1 = (const float*)d_in[6];
  const float* b_ih1 = (const float*)d_in[7];
  const float* b_hh1 = (const float*)d_in[8];
  const float* emb_w = (const float*)d_in[9];
  const float* emb_b = (const float*)d_in[10];
  const float* fc_w  = (const float*)d_in[11];
  const float* fc_b  = (const float*)d_in[12];

  // -------- workspace (~144 MB, fits L3 with headroom) --------
  char* ws = (char*)d_ws;
  size_t off = 0;
  auto alloc = [&](size_t bytes) -> void* {
    void* p = ws + off;
    off += (bytes + 255) & ~(size_t)255;
    return p;
  };
  const size_t bin_b  = (size_t)2 * G4 * KIN * 2;               // 8.39 MB
  const size_t brec_b = (size_t)2 * G4 * H_SZ * 2;              // 4.19 MB
  const size_t xb_b   = (size_t)TSTEPS * B_SZ * 32 * 4;         // 5.50 MB
  const size_t h_b    = (size_t)2 * B_SZ * H_SZ * 2;            // 4.19 MB
  const size_t c_b    = (size_t)2 * B_SZ * H_SZ * 4;            // 8.39 MB
  const size_t seq_b  = (size_t)TSTEPS * B_SZ * (2 * H_SZ) * 2; // 88.08 MB
  const size_t z_b    = (size_t)B_SZ * (2 * H_SZ) * 4;          // 8.39 MB

  unsigned short* Bin0  = (unsigned short*)alloc(bin_b);   // L0-only; zacc aliases
  unsigned short* Bin1  = (unsigned short*)alloc(bin_b);
  unsigned short* Bh0   = (unsigned short*)alloc(brec_b);
  unsigned short* Bl0   = (unsigned short*)alloc(brec_b);
  unsigned short* Bh1   = (unsigned short*)alloc(brec_b);
  unsigned short* Bl1   = (unsigned short*)alloc(brec_b);
  float*          bias0 = (float*)alloc((size_t)2 * G4 * 4);
  float*          bias1 = (float*)alloc((size_t)2 * G4 * 4);
  unsigned int*   xbits = (unsigned int*)alloc(xb_b);
  unsigned short* hA    = (unsigned short*)alloc(h_b);
  unsigned short* hB    = (unsigned short*)alloc(h_b);
  float*          cst   = (float*)alloc(c_b);
  unsigned short* seq0  = (unsigned short*)alloc(seq_b);
  float*          zacc  = (float*)Bin0;   // Bin0 (8.39 MB) dead after layer 0; z_b == bin_b

  // -------- prep --------
  {
    size_t ti = (size_t)2 * G4 * KIN;
    prep_in0_kernel<<<(int)((ti + 255) / 256), 256, 0, stream>>>(w_ih0, Bin0);
    prep_in1_kernel<<<(int)((ti + 255) / 256), 256, 0, stream>>>(w_ih1, Bin1);
    size_t tr = (size_t)2 * G4 * H_SZ;
    prep_rec_kernel<<<(int)((tr + 255) / 256), 256, 0, stream>>>(w_hh0, Bh0, Bl0);
    prep_rec_kernel<<<(int)((tr + 255) / 256), 256, 0, stream>>>(w_hh1, Bh1, Bl1);
    prep_b_kernel<<<16, 256, 0, stream>>>(b_ih0, b_hh0, b_ih1, b_hh1, bias0, bias1);
    prep_x_kernel<<<(B_SZ * 32 + 255) / 256, 256, 0, stream>>>(x, xbits);
  }

  // -------- layer 0 --------
  hipMemsetAsync(hA, 0, h_b, stream);
  hipMemsetAsync(cst, 0, c_b, stream);
  for (int s = 0; s < TSTEPS; ++s) {
    const unsigned short* hin  = (s & 1) ? hB : hA;
    unsigned short*       hout = (s & 1) ? hA : hB;
    fused_kernel<0><<<512, 512, SMEM_BYTES, stream>>>(
        xbits, nullptr, Bin0, Bh0, Bl0, bias0, hin, hout, cst,
        seq0, nullptr, nullptr, s);
  }

  // -------- layer 1 --------
  hipMemsetAsync(hA, 0, h_b, stream);
  hipMemsetAsync(cst, 0, c_b, stream);
  hipMemsetAsync(zacc, 0, z_b, stream);
  for (int s = 0; s < TSTEPS; ++s) {
    const unsigned short* hin  = (s & 1) ? hB : hA;
    unsigned short*       hout = (s & 1) ? hA : hB;
    fused_kernel<1><<<512, 512, SMEM_BYTES, stream>>>(
        nullptr, seq0, Bin1, Bh1, Bl1, bias1, hin, hout, cst,
        nullptr, zacc, emb_w, s);
  }

  // -------- fc --------
  final_kernel<<<B_SZ, 256, 0, stream>>>(zacc, emb_b, fc_w, fc_b, (float*)d_out);
}